// Round 3
// baseline (104.859 us; speedup 1.0000x reference)
//
#include <hip/hip_runtime.h>

// SWT level-1 (db2, norm=True) along channel axis.
// x: [8, 64, 128, 128] f32 -> out: [8, 128, 128, 128] f32 (cA || cD on axis 1).
// cA[o] = lo3*x[o-1] + lo2*x[o] + lo1*x[o+1] + lo0*x[o+2]  (channels mod 64)
//
// R3 = DIAGNOSTIC: kernel source is byte-identical to R2; it is launched TWICE
// (idempotent: pure function of x, same output both times). Purpose: the timed
// graph contains a 41.5us poison-fill + dozens of tiny restore memsets that
// rocprof_to_text hides, so the kernel's own cost is unidentifiable from the
// top-5 (it never ranks). T_kernel = dur_R3 - dur_R2 measures it directly.
//   ~131-136us => kernel ~40+us, 2.5x headroom, keep optimizing memory path.
//   ~106-111us => kernel ~15-20us ~= roofline (101 MB @ 6.3 TB/s), declare done.
// R1/R2 established: occupancy (2 vs 8 blocks/CU) and store type (nt vs plain)
// both irrelevant (89.2 / 90.1 / 91.1 us — all within noise).

#define HW4 4096   // (128*128)/4 float4 per channel
#define NC  64     // input channels
#define CH  4      // output channels per block chunk

typedef float f4 __attribute__((ext_vector_type(4)));

__global__ __launch_bounds__(256, 8) void swt_db2_kernel(
    const f4* __restrict__ x, f4* __restrict__ out) {
  const int s4 = blockIdx.x * 256 + threadIdx.x;   // spatial float4 slot
  const int c0 = blockIdx.y * CH;                  // first output channel
  const int b  = blockIdx.z;

  const f4* xb = x   + (size_t)b * NC * HW4 + s4;
  f4*       ob = out + (size_t)b * 2 * NC * HW4 + s4;

  const float lo0 = -0.09150635094610966f;
  const float lo1 =  0.15849364905389033f;
  const float lo2 =  0.59150635094610960f;
  const float lo3 =  0.34150635094610970f;
  const float hi0 = -0.34150635094610970f;
  const float hi1 =  0.59150635094610960f;
  const float hi2 = -0.15849364905389033f;
  const float hi3 = -0.09150635094610966f;

  // Load CH+3 = 7 input channels (c0-1 .. c0+5 mod 64), all coalesced,
  // issued back-to-back for memory-level parallelism.
  f4 v[CH + 3];
#pragma unroll
  for (int k = 0; k < CH + 3; ++k) {
    const int c = (c0 - 1 + k) & (NC - 1);
    v[k] = xb[(size_t)c * HW4];
  }

#pragma unroll
  for (int i = 0; i < CH; ++i) {
    const int o = c0 + i;
    f4 a, d;
#pragma unroll
    for (int f = 0; f < 4; ++f) {
      a[f] = fmaf(lo3, v[i][f], fmaf(lo2, v[i+1][f],
               fmaf(lo1, v[i+2][f], lo0 * v[i+3][f])));
      d[f] = fmaf(hi3, v[i][f], fmaf(hi2, v[i+1][f],
               fmaf(hi1, v[i+2][f], hi0 * v[i+3][f])));
    }
    ob[(size_t)o * HW4]        = a;
    ob[(size_t)(o + NC) * HW4] = d;
  }
}

extern "C" void kernel_launch(void* const* d_in, const int* in_sizes, int n_in,
                              void* d_out, int out_size, void* d_ws, size_t ws_size,
                              hipStream_t stream) {
  const f4* x   = (const f4*)d_in[0];
  f4*       out = (f4*)d_out;
  // grid: x = spatial chunks (4096/256 = 16), y = channel chunks (64/4 = 16), z = batch (8)
  dim3 grid(HW4 / 256, NC / CH, 8);
  dim3 block(256);
  // Launch TWICE (diagnostic, see header). Output is idempotent.
  hipLaunchKernelGGL(swt_db2_kernel, grid, block, 0, stream, x, out);
  hipLaunchKernelGGL(swt_db2_kernel, grid, block, 0, stream, x, out);
}

// Round 4
// 89.659 us; speedup vs baseline: 1.1695x; 1.1695x over previous
//
#include <hip/hip_runtime.h>

// SWT level-1 (db2, norm=True) along channel axis.
// x: [8, 64, 128, 128] f32 -> out: [8, 128, 128, 128] f32 (cA || cD on axis 1).
// cA[o] = lo3*x[o-1] + lo2*x[o] + lo1*x[o+1] + lo0*x[o+2]  (channels mod 64)
//
// ROOFLINE (established R3): the kernel's own cost is ~14 us (double-launch
// diagnostic: 104.9 - 91.1 us), vs ideal 100 MB @ 6.3 TB/s = 16 us -> the
// kernel is AT the achievable HBM roofline (reads partly L3-served). The
// remaining ~77 us of dur_us is fixed harness cost (42 us poison-fill +
// restore memsets + gaps) outside kernel_launch's control. R1/R2 established
// occupancy (2 vs 8 blocks/CU) and store type (nt vs plain) are both within
// noise — consistent with the kernel being a ~15% minority of the timed graph.
// This version: single launch (diagnostic second dispatch reverted).

#define HW4 4096   // (128*128)/4 float4 per channel
#define NC  64     // input channels
#define CH  4      // output channels per block chunk

typedef float f4 __attribute__((ext_vector_type(4)));

__global__ __launch_bounds__(256, 8) void swt_db2_kernel(
    const f4* __restrict__ x, f4* __restrict__ out) {
  const int s4 = blockIdx.x * 256 + threadIdx.x;   // spatial float4 slot
  const int c0 = blockIdx.y * CH;                  // first output channel
  const int b  = blockIdx.z;

  const f4* xb = x   + (size_t)b * NC * HW4 + s4;
  f4*       ob = out + (size_t)b * 2 * NC * HW4 + s4;

  const float lo0 = -0.09150635094610966f;
  const float lo1 =  0.15849364905389033f;
  const float lo2 =  0.59150635094610960f;
  const float lo3 =  0.34150635094610970f;
  const float hi0 = -0.34150635094610970f;
  const float hi1 =  0.59150635094610960f;
  const float hi2 = -0.15849364905389033f;
  const float hi3 = -0.09150635094610966f;

  // Load CH+3 = 7 input channels (c0-1 .. c0+5 mod 64), all coalesced,
  // issued back-to-back for memory-level parallelism.
  f4 v[CH + 3];
#pragma unroll
  for (int k = 0; k < CH + 3; ++k) {
    const int c = (c0 - 1 + k) & (NC - 1);
    v[k] = xb[(size_t)c * HW4];
  }

#pragma unroll
  for (int i = 0; i < CH; ++i) {
    const int o = c0 + i;
    f4 a, d;
#pragma unroll
    for (int f = 0; f < 4; ++f) {
      a[f] = fmaf(lo3, v[i][f], fmaf(lo2, v[i+1][f],
               fmaf(lo1, v[i+2][f], lo0 * v[i+3][f])));
      d[f] = fmaf(hi3, v[i][f], fmaf(hi2, v[i+1][f],
               fmaf(hi1, v[i+2][f], hi0 * v[i+3][f])));
    }
    ob[(size_t)o * HW4]        = a;
    ob[(size_t)(o + NC) * HW4] = d;
  }
}

extern "C" void kernel_launch(void* const* d_in, const int* in_sizes, int n_in,
                              void* d_out, int out_size, void* d_ws, size_t ws_size,
                              hipStream_t stream) {
  const f4* x   = (const f4*)d_in[0];
  f4*       out = (f4*)d_out;
  // grid: x = spatial chunks (4096/256 = 16), y = channel chunks (64/4 = 16), z = batch (8)
  dim3 grid(HW4 / 256, NC / CH, 8);
  dim3 block(256);
  hipLaunchKernelGGL(swt_db2_kernel, grid, block, 0, stream, x, out);
}